// Round 1
// baseline (983.212 us; speedup 1.0000x reference)
//
#include <hip/hip_runtime.h>
#include <stdint.h>

#define DEVI __device__ __forceinline__

typedef __attribute__((ext_vector_type(8))) short bf16x8;   // 8 bf16 (4 VGPRs)
typedef __attribute__((ext_vector_type(4))) float f32x4;    // MFMA C/D

static constexpr int D = 4096;    // d_in == d_out
static constexpr int M = 16384;   // bs*seq rows

// exact RNE float -> bf16 bits
DEVI unsigned short f2bf(float f) {
  union { float f; unsigned u; } a; a.f = f;
  unsigned r = a.u + 0x7fffu + ((a.u >> 16) & 1u);
  return (unsigned short)(r >> 16);
}

// async global->LDS, 16B per lane; LDS dest is wave-uniform base + lane*16
DEVI void gload_lds16(const void* g, void* l) {
  __builtin_amdgcn_global_load_lds(
      (__attribute__((address_space(1))) void*)(uintptr_t)g,
      (__attribute__((address_space(3))) void*)l,
      16, 0, 0);
}

// ---------------- Kernel A: w_norm (double) + W -> bf16 ----------------
__global__ __launch_bounds__(256) void k_wnorm(const float* __restrict__ w,
                                               double* __restrict__ wn_d,
                                               unsigned short* __restrict__ wbf) {
  const int col = blockIdx.x * 256 + threadIdx.x;   // input-channel index
  const int r0 = blockIdx.y * 256;                  // output-row chunk
  double s = 0.0;
  for (int r = r0; r < r0 + 256; ++r) {
    float v = w[(size_t)r * D + col];
    wbf[(size_t)r * D + col] = f2bf(v);
    s += (double)v * (double)v;
  }
  atomicAdd(&wn_d[col], s);
}

__global__ void k_wnf(const double* __restrict__ wn_d, float* __restrict__ wn_f) {
  int i = blockIdx.x * blockDim.x + threadIdx.x;
  if (i < D) wn_f[i] = (float)wn_d[i];
}

// ---------------- Kernel B: 2:4 prune + variance-correct, -> bf16 -------
__global__ __launch_bounds__(256) void k_prune(const float* __restrict__ x,
                                               const float* __restrict__ wn_f,
                                               unsigned short* __restrict__ xs) {
  const int row = blockIdx.x;
  const float* xr = x + (size_t)row * D;
  unsigned short* xo = xs + (size_t)row * D;
  const int t = threadIdx.x;

  float kept[4][4];
  float sx = 0.f, sxx = 0.f, ss = 0.f, sss = 0.f;

#pragma unroll
  for (int i = 0; i < 4; ++i) {
    const int g = t + i * 256;  // group of 4 channels
    const float4 v  = *(const float4*)(xr + 4 * (size_t)g);
    const float4 wv = *(const float4*)(wn_f + 4 * (size_t)g);
    float xv[4] = {v.x, v.y, v.z, v.w};
    float m[4]  = {fabsf(v.x) * wv.x, fabsf(v.y) * wv.y,
                   fabsf(v.z) * wv.z, fabsf(v.w) * wv.w};
    // top-2 of 4, ties -> lowest index (matches jax.lax.top_k)
    int i1 = 0;
#pragma unroll
    for (int j = 1; j < 4; ++j) if (m[j] > m[i1]) i1 = j;
    int i2 = (i1 == 0) ? 1 : 0;
#pragma unroll
    for (int j = 0; j < 4; ++j) if (j != i1 && j != i2 && m[j] > m[i2]) i2 = j;
#pragma unroll
    for (int j = 0; j < 4; ++j) {
      bool keep = (j == i1) || (j == i2);
      float kv = keep ? xv[j] : 0.f;
      kept[i][j] = kv;
      sx  += xv[j];
      sxx += xv[j] * xv[j];
      ss  += kv;
      sss += kv * kv;
    }
  }

  // wave reduce (64 lanes), then block reduce
#pragma unroll
  for (int o = 32; o > 0; o >>= 1) {
    sx  += __shfl_down(sx, o);
    sxx += __shfl_down(sxx, o);
    ss  += __shfl_down(ss, o);
    sss += __shfl_down(sss, o);
  }
  __shared__ float wp[4][4];
  __shared__ float s_scale;
  const int wid = t >> 6, lane = t & 63;
  if (lane == 0) { wp[wid][0] = sx; wp[wid][1] = sxx; wp[wid][2] = ss; wp[wid][3] = sss; }
  __syncthreads();
  if (t == 0) {
    float SX = 0, SXX = 0, SS = 0, SSS = 0;
    for (int u = 0; u < 4; ++u) { SX += wp[u][0]; SXX += wp[u][1]; SS += wp[u][2]; SSS += wp[u][3]; }
    // var ratio: (n-1) denominators cancel
    float vx = SXX - SX * SX * (1.f / 4096.f);
    float vs = SSS - SS * SS * (1.f / 4096.f);
    s_scale = sqrtf(vx / vs);
  }
  __syncthreads();
  const float sc = s_scale;

#pragma unroll
  for (int i = 0; i < 4; ++i) {
    const int g = t + i * 256;
    ushort4 o;
    o.x = f2bf(kept[i][0] * sc);
    o.y = f2bf(kept[i][1] * sc);
    o.z = f2bf(kept[i][2] * sc);
    o.w = f2bf(kept[i][3] * sc);
    *(ushort4*)(xo + 4 * (size_t)g) = o;
  }
}

// ---------------- Kernel C: bf16 GEMM, C[m][n] = sum_k A[m][k]*B[n][k] ----
// m97 structure: 128x128 tile, BK=32, 4 waves (2x2), 4x4 16x16x32 frags/wave,
// global_load_lds width=16, linear LDS (T2 swizzle null on 2-phase structure).
__global__ __launch_bounds__(256) void k_gemm(const unsigned short* __restrict__ A,  // [M,K] bf16
                                              const unsigned short* __restrict__ B,  // [N,K] bf16
                                              float* __restrict__ C) {               // [M,N]
  __shared__ __align__(16) short As[128 * 32];
  __shared__ __align__(16) short Bs[128 * 32];

  const int t = threadIdx.x;
  const int w = t >> 6;
  const int lane = t & 63;
  const int m0 = blockIdx.y * 128;
  const int n0 = blockIdx.x * 128;
  const int wm = (w >> 1) * 64;   // wave row offset in tile
  const int wn = (w & 1) * 64;    // wave col offset in tile

  const int fr = lane & 15;         // row (A) / col (B) within 16-frag
  const int fk = (lane >> 4) * 8;   // k offset within 32

  f32x4 acc[4][4] = {};

  for (int k0 = 0; k0 < D; k0 += 32) {
    // stage A tile 128x32 (512 x 16B chunks) and B tile, 2 issues each/thread
#pragma unroll
    for (int i = 0; i < 2; ++i) {
      const int ci = i * 256 + t;           // 16B-chunk index
      const int row = ci >> 2;              // 4 chunks per 32-elem row
      const int ko = (ci & 3) * 8;
      gload_lds16(A + (size_t)(m0 + row) * D + k0 + ko,
                  &As[(size_t)(i * 256 + (t & ~63)) * 8]);
    }
#pragma unroll
    for (int i = 0; i < 2; ++i) {
      const int ci = i * 256 + t;
      const int row = ci >> 2;
      const int ko = (ci & 3) * 8;
      gload_lds16(B + (size_t)(n0 + row) * D + k0 + ko,
                  &Bs[(size_t)(i * 256 + (t & ~63)) * 8]);
    }
    __syncthreads();   // compiler drains vmcnt before s_barrier

    bf16x8 a[4], b[4];
#pragma unroll
    for (int fm = 0; fm < 4; ++fm)
      a[fm] = *(const bf16x8*)&As[(wm + fm * 16 + fr) * 32 + fk];
#pragma unroll
    for (int fn = 0; fn < 4; ++fn)
      b[fn] = *(const bf16x8*)&Bs[(wn + fn * 16 + fr) * 32 + fk];
#pragma unroll
    for (int fm = 0; fm < 4; ++fm)
#pragma unroll
      for (int fn = 0; fn < 4; ++fn)
        acc[fm][fn] = __builtin_amdgcn_mfma_f32_16x16x32_bf16(a[fm], b[fn], acc[fm][fn], 0, 0, 0);
    __syncthreads();
  }

  // epilogue: C/D layout col=lane&15, row=(lane>>4)*4+i  [m89/m91 verified]
  const int orow = (lane >> 4) * 4;
  const int ocol = lane & 15;
#pragma unroll
  for (int fm = 0; fm < 4; ++fm)
#pragma unroll
    for (int fn = 0; fn < 4; ++fn)
#pragma unroll
      for (int i = 0; i < 4; ++i)
        C[(size_t)(m0 + wm + fm * 16 + orow + i) * D + (n0 + wn + fn * 16 + ocol)] =
            acc[fm][fn][i];
}

extern "C" void kernel_launch(void* const* d_in, const int* in_sizes, int n_in,
                              void* d_out, int out_size, void* d_ws, size_t ws_size,
                              hipStream_t stream) {
  const float* x = (const float*)d_in[0];   // [4,4096,4096] fp32
  const float* w = (const float*)d_in[1];   // [4096,4096] fp32
  float* out = (float*)d_out;               // [16384,4096] fp32

  char* ws = (char*)d_ws;
  double* wn_d = (double*)ws;                                   // 32 KB
  float* wn_f = (float*)(ws + 32768);                           // 16 KB
  unsigned short* wbf = (unsigned short*)(ws + 49152);          // 33.5 MB
  unsigned short* xsb = (unsigned short*)(ws + 49152 + (size_t)D * D * 2);  // 134 MB

  hipMemsetAsync(wn_d, 0, D * sizeof(double), stream);
  k_wnorm<<<dim3(16, 16), 256, 0, stream>>>(w, wn_d, wbf);
  k_wnf<<<16, 256, 0, stream>>>(wn_d, wn_f);
  k_prune<<<M, 256, 0, stream>>>(x, wn_f, xsb);
  k_gemm<<<dim3(D / 128, M / 128), 256, 0, stream>>>(xsb, wbf, out);
}

// Round 2
// 621.003 us; speedup vs baseline: 1.5833x; 1.5833x over previous
//
#include <hip/hip_runtime.h>
#include <stdint.h>

#define DEVI __device__ __forceinline__

typedef __attribute__((ext_vector_type(8))) short bf16x8;   // 8 bf16 (4 VGPRs)
typedef __attribute__((ext_vector_type(4))) float f32x4;    // MFMA C/D

static constexpr int D = 4096;    // d_in == d_out == K == N
static constexpr int M = 16384;   // bs*seq rows
static constexpr int NT = 64;     // K / 64 K-tiles

// exact RNE float -> bf16 bits
DEVI unsigned short f2bf(float f) {
  union { float f; unsigned u; } a; a.f = f;
  unsigned r = a.u + 0x7fffu + ((a.u >> 16) & 1u);
  return (unsigned short)(r >> 16);
}

// async global->LDS, 16B per lane; LDS dest is wave-uniform base + lane*16
DEVI void gload_lds16(const void* g, void* l) {
  __builtin_amdgcn_global_load_lds(
      (__attribute__((address_space(1))) void*)(uintptr_t)g,
      (__attribute__((address_space(3))) void*)l,
      16, 0, 0);
}

DEVI f32x4 MFMA(bf16x8 a, bf16x8 b, f32x4 c) {
  return __builtin_amdgcn_mfma_f32_16x16x32_bf16(a, b, c, 0, 0, 0);
}

// ---------------- Kernel A: w_norm (double) + W -> bf16 ----------------
__global__ __launch_bounds__(256) void k_wnorm(const float* __restrict__ w,
                                               double* __restrict__ wn_d,
                                               unsigned short* __restrict__ wbf) {
  const int col = blockIdx.x * 256 + threadIdx.x;
  const int r0 = blockIdx.y * 256;
  double s = 0.0;
  for (int r = r0; r < r0 + 256; ++r) {
    float v = w[(size_t)r * D + col];
    wbf[(size_t)r * D + col] = f2bf(v);
    s += (double)v * (double)v;
  }
  atomicAdd(&wn_d[col], s);
}

__global__ void k_wnf(const double* __restrict__ wn_d, float* __restrict__ wn_f) {
  int i = blockIdx.x * blockDim.x + threadIdx.x;
  if (i < D) wn_f[i] = (float)wn_d[i];
}

// ---------------- Kernel B: 2:4 prune + variance-correct, -> bf16 -------
__global__ __launch_bounds__(256) void k_prune(const float* __restrict__ x,
                                               const float* __restrict__ wn_f,
                                               unsigned short* __restrict__ xs) {
  const int row = blockIdx.x;
  const float* xr = x + (size_t)row * D;
  unsigned short* xo = xs + (size_t)row * D;
  const int t = threadIdx.x;

  float kept[4][4];
  float sx = 0.f, sxx = 0.f, ss = 0.f, sss = 0.f;

#pragma unroll
  for (int i = 0; i < 4; ++i) {
    const int g = t + i * 256;
    const float4 v  = *(const float4*)(xr + 4 * (size_t)g);
    const float4 wv = *(const float4*)(wn_f + 4 * (size_t)g);
    float xv[4] = {v.x, v.y, v.z, v.w};
    float m[4]  = {fabsf(v.x) * wv.x, fabsf(v.y) * wv.y,
                   fabsf(v.z) * wv.z, fabsf(v.w) * wv.w};
    int i1 = 0;
#pragma unroll
    for (int j = 1; j < 4; ++j) if (m[j] > m[i1]) i1 = j;
    int i2 = (i1 == 0) ? 1 : 0;
#pragma unroll
    for (int j = 0; j < 4; ++j) if (j != i1 && j != i2 && m[j] > m[i2]) i2 = j;
#pragma unroll
    for (int j = 0; j < 4; ++j) {
      bool keep = (j == i1) || (j == i2);
      float kv = keep ? xv[j] : 0.f;
      kept[i][j] = kv;
      sx += xv[j]; sxx += xv[j] * xv[j]; ss += kv; sss += kv * kv;
    }
  }

#pragma unroll
  for (int o = 32; o > 0; o >>= 1) {
    sx  += __shfl_down(sx, o);
    sxx += __shfl_down(sxx, o);
    ss  += __shfl_down(ss, o);
    sss += __shfl_down(sss, o);
  }
  __shared__ float wp[4][4];
  __shared__ float s_scale;
  const int wid = t >> 6, lane = t & 63;
  if (lane == 0) { wp[wid][0] = sx; wp[wid][1] = sxx; wp[wid][2] = ss; wp[wid][3] = sss; }
  __syncthreads();
  if (t == 0) {
    float SX = 0, SXX = 0, SS = 0, SSS = 0;
    for (int u = 0; u < 4; ++u) { SX += wp[u][0]; SXX += wp[u][1]; SS += wp[u][2]; SSS += wp[u][3]; }
    float vx = SXX - SX * SX * (1.f / 4096.f);
    float vs = SSS - SS * SS * (1.f / 4096.f);
    s_scale = sqrtf(vx / vs);
  }
  __syncthreads();
  const float sc = s_scale;

#pragma unroll
  for (int i = 0; i < 4; ++i) {
    const int g = t + i * 256;
    ushort4 o;
    o.x = f2bf(kept[i][0] * sc);
    o.y = f2bf(kept[i][1] * sc);
    o.z = f2bf(kept[i][2] * sc);
    o.w = f2bf(kept[i][3] * sc);
    *(ushort4*)(xo + 4 * (size_t)g) = o;
  }
}

// ---------------- Kernel C: bf16 GEMM, 256x256 tile, 8-phase schedule ----
// C[m][n] = sum_k A[m][k]*B[n][k].  BK=64 split in 2 k-halves; LDS regions
// [parity][khalf] 256x32 bf16 (16KB each), A at 0, B at +64KB. T2 swizzle:
// 16B-chunk c ^= (row>>1)&3 (pre-swizzled global source + swizzled ds_read,
// linear global_load_lds dest). Counted vmcnt(4) once per K-tile (T4),
// setprio around MFMA (T5), XCD-swizzled blockIdx (T1).
__global__ __launch_bounds__(512, 2) void k_gemm(const unsigned short* __restrict__ A,  // [M,K]
                                                 const unsigned short* __restrict__ B,  // [N,K]
                                                 float* __restrict__ C) {               // [M,N]
  extern __shared__ char smem[];   // 131072 bytes

  const int tid  = threadIdx.x;
  const int lane = tid & 63;
  const int wid  = tid >> 6;
  const int wr   = wid >> 2;   // 0..1  (row half)
  const int wc   = wid & 3;    // 0..3  (col quarter)

  // T1: XCD swizzle (1024 blocks, divisible by 8)
  const int bid = blockIdx.x;
  const int swz = (bid & 7) * 128 + (bid >> 3);
  const int m0 = (swz >> 4) * 256;   // 64 row tiles
  const int n0 = (swz & 15) * 256;   // 16 col tiles

  // staging: 1024 chunks/half-tile region, 2 issues/thread
  const int rs = tid >> 2;                                  // 0..127
  const int ks = ((tid & 3) ^ ((rs >> 1) & 3)) * 8;         // swizzled k-elem off
  const unsigned short* Ar0 = A + (size_t)(m0 + rs) * D + ks;
  const unsigned short* Ar1 = Ar0 + (size_t)128 * D;
  const unsigned short* Br0 = B + (size_t)(n0 + rs) * D + ks;
  const unsigned short* Br1 = Br0 + (size_t)128 * D;
  char* ldst = smem + tid * 16;

  // frag-read byte offsets (within a 16KB region)
  const int swz16 = (((lane >> 4) ^ ((lane >> 1) & 3)) << 4);
  const int aRd = (wr * 128 + (lane & 15)) * 64 + swz16;    // + fm*1024 + region
  const int bRd = (wc * 64 + (lane & 15)) * 64 + swz16;     // + fn*1024 + region

#define STAGE_A(Preg, H, kt) do {                                    \
    const int _rb = ((Preg) * 2 + (H)) * 16384;                      \
    const int _ko = (kt) * 64 + (H) * 32;                            \
    gload_lds16(Ar0 + _ko, ldst + _rb);                              \
    gload_lds16(Ar1 + _ko, ldst + _rb + 8192);                       \
  } while (0)
#define STAGE_B(Preg, H, kt) do {                                    \
    const int _rb = 65536 + ((Preg) * 2 + (H)) * 16384;              \
    const int _ko = (kt) * 64 + (H) * 32;                            \
    gload_lds16(Br0 + _ko, ldst + _rb);                              \
    gload_lds16(Br1 + _ko, ldst + _rb + 8192);                       \
  } while (0)

  f32x4 acc[8][4] = {};

  // ---- prologue: tile0 (4 halves) + tile1 kh0 (2 halves) = 12 loads ----
  STAGE_A(0, 0, 0); STAGE_B(0, 0, 0);
  STAGE_A(0, 1, 0); STAGE_B(0, 1, 0);
  STAGE_A(1, 0, 1); STAGE_B(1, 0, 1);
  asm volatile("s_waitcnt vmcnt(4)" ::: "memory");
  __builtin_amdgcn_s_barrier();

  for (int t = 0; t < NT; ++t) {
    const int P  = t & 1;
    const int Pn = P ^ 1;
    const int tn1 = (t + 1 < NT) ? t + 1 : NT - 1;
    const int tn2 = (t + 2 < NT) ? t + 2 : NT - 1;
    const int abase0 = P * 32768;            // A region (P,0)
    const int abase1 = P * 32768 + 16384;    // A region (P,1)
    const int bbase0 = 65536 + P * 32768;    // B region (P,0)
    const int bbase1 = 65536 + P * 32768 + 16384;

    bf16x8 a[8], b0, b1, b2, b3;

    // ---------- phase 1: kh0, fn 0-1 ----------
#pragma unroll
    for (int fm = 0; fm < 8; ++fm)
      a[fm] = *(const bf16x8*)(smem + abase0 + aRd + fm * 1024);
    b0 = *(const bf16x8*)(smem + bbase0 + bRd);
    b1 = *(const bf16x8*)(smem + bbase0 + bRd + 1024);
    STAGE_A(Pn, 1, tn1);
    __builtin_amdgcn_s_barrier();
    asm volatile("s_waitcnt lgkmcnt(0)" ::: "memory");
    __builtin_amdgcn_s_setprio(1);
#pragma unroll
    for (int fm = 0; fm < 8; ++fm) acc[fm][0] = MFMA(a[fm], b0, acc[fm][0]);
#pragma unroll
    for (int fm = 0; fm < 8; ++fm) acc[fm][1] = MFMA(a[fm], b1, acc[fm][1]);
    __builtin_amdgcn_s_setprio(0);
    __builtin_amdgcn_s_barrier();

    // ---------- phase 2: kh0, fn 2-3 ----------
    b2 = *(const bf16x8*)(smem + bbase0 + bRd + 2048);
    b3 = *(const bf16x8*)(smem + bbase0 + bRd + 3072);
    STAGE_B(Pn, 1, tn1);
    __builtin_amdgcn_s_barrier();
    asm volatile("s_waitcnt lgkmcnt(0)" ::: "memory");
    __builtin_amdgcn_s_setprio(1);
#pragma unroll
    for (int fm = 0; fm < 8; ++fm) acc[fm][2] = MFMA(a[fm], b2, acc[fm][2]);
#pragma unroll
    for (int fm = 0; fm < 8; ++fm) acc[fm][3] = MFMA(a[fm], b3, acc[fm][3]);
    __builtin_amdgcn_s_setprio(0);
    __builtin_amdgcn_s_barrier();

    // ---------- phase 3: kh1, fn 0-1 ----------
#pragma unroll
    for (int fm = 0; fm < 8; ++fm)
      a[fm] = *(const bf16x8*)(smem + abase1 + aRd + fm * 1024);
    b0 = *(const bf16x8*)(smem + bbase1 + bRd);
    b1 = *(const bf16x8*)(smem + bbase1 + bRd + 1024);
    STAGE_A(P, 0, tn2);   // parity(t+2) == P
    __builtin_amdgcn_s_barrier();
    asm volatile("s_waitcnt lgkmcnt(0)" ::: "memory");
    __builtin_amdgcn_s_setprio(1);
#pragma unroll
    for (int fm = 0; fm < 8; ++fm) acc[fm][0] = MFMA(a[fm], b0, acc[fm][0]);
#pragma unroll
    for (int fm = 0; fm < 8; ++fm) acc[fm][1] = MFMA(a[fm], b1, acc[fm][1]);
    __builtin_amdgcn_s_setprio(0);
    __builtin_amdgcn_s_barrier();

    // ---------- phase 4: kh1, fn 2-3 (boundary vmcnt) ----------
    b2 = *(const bf16x8*)(smem + bbase1 + bRd + 2048);
    b3 = *(const bf16x8*)(smem + bbase1 + bRd + 3072);
    STAGE_B(P, 0, tn2);
    asm volatile("s_waitcnt vmcnt(4)" ::: "memory");
    __builtin_amdgcn_s_barrier();
    asm volatile("s_waitcnt lgkmcnt(0)" ::: "memory");
    __builtin_amdgcn_s_setprio(1);
#pragma unroll
    for (int fm = 0; fm < 8; ++fm) acc[fm][2] = MFMA(a[fm], b2, acc[fm][2]);
#pragma unroll
    for (int fm = 0; fm < 8; ++fm) acc[fm][3] = MFMA(a[fm], b3, acc[fm][3]);
    __builtin_amdgcn_s_setprio(0);
    __builtin_amdgcn_s_barrier();
  }
#undef STAGE_A
#undef STAGE_B

  // ---- epilogue: C/D layout col=lane&15, row=(lane>>4)*4+i ----
  const int orow = (lane >> 4) * 4;
  const int ocol = lane & 15;
  float* Cw = C + (size_t)(m0 + wr * 128 + orow) * D + n0 + wc * 64 + ocol;
#pragma unroll
  for (int fm = 0; fm < 8; ++fm)
#pragma unroll
    for (int fn = 0; fn < 4; ++fn)
#pragma unroll
      for (int i = 0; i < 4; ++i)
        Cw[(size_t)(fm * 16 + i) * D + fn * 16] = acc[fm][fn][i];
}

extern "C" void kernel_launch(void* const* d_in, const int* in_sizes, int n_in,
                              void* d_out, int out_size, void* d_ws, size_t ws_size,
                              hipStream_t stream) {
  const float* x = (const float*)d_in[0];   // [4,4096,4096] fp32
  const float* w = (const float*)d_in[1];   // [4096,4096] fp32
  float* out = (float*)d_out;               // [16384,4096] fp32

  char* ws = (char*)d_ws;
  double* wn_d = (double*)ws;                                   // 32 KB
  float* wn_f = (float*)(ws + 32768);                           // 16 KB
  unsigned short* wbf = (unsigned short*)(ws + 49152);          // 33.5 MB
  unsigned short* xsb = (unsigned short*)(ws + 49152 + (size_t)D * D * 2);  // 134 MB

  hipMemsetAsync(wn_d, 0, D * sizeof(double), stream);
  k_wnorm<<<dim3(16, 16), 256, 0, stream>>>(w, wn_d, wbf);
  k_wnf<<<16, 256, 0, stream>>>(wn_d, wn_f);
  k_prune<<<M, 256, 0, stream>>>(x, wn_f, xsb);
  k_gemm<<<dim3((M / 256) * (D / 256)), 512, 131072, stream>>>(xsb, wbf, out);
}